// Round 13
// baseline (57.068 us; speedup 1.0000x reference)
//
#include <hip/hip_runtime.h>

// MoE gate: logits = x @ W^T (x:[16384,2048] f32, W:[64,2048] f32),
// softmax over 64 experts, top-8 -> weights f32 + indices stored as f32.
//
// R13: amortize W over 128 tokens/stream without losing grid width.
//  grid 256 = 128 token-groups(128 tok) x 2 K-halves; 8 waves =
//  4 tok-subblocks(tw) x 2 K-subquarters(kq2). Wave = R8's HW-proven
//  32tok x 64exp x 512K SLICE schedule VERBATIM (same vmcnt literals).
//  The 4 tw-waves per kq2 read an IDENTICAL W stream -> MSHR/L1 merge;
//  PBAR every 4 slices bounds drift. In-block LDS combine of kq2 pairs,
//  pl[2][NT][64] partials, coalesced 2-way combine + softmax/top-8.
// Per-CU bytes: x 512KB + W ~384KB(merged) + pl 33KB ~= 0.93MB (R8: 1.25MB).

typedef __attribute__((ext_vector_type(8))) short short8;
typedef __attribute__((ext_vector_type(16))) float f32x16;
typedef __attribute__((ext_vector_type(4))) float f32x4;
typedef __attribute__((ext_vector_type(4))) unsigned int u32x4;

#define NT    16384
#define DIMK  2048
#define NE    64
#define TOPKK 8
#define WPK_BYTES 786432
#define PL_BYTES  (2 * NT * NE * 4)           // 8388608
#define WS_NEED   (WPK_BYTES + PL_BYTES)

union U4S8 { unsigned int u[4]; short8 s; u32x4 v; };

__device__ __forceinline__ short8 as_s8(u32x4 v) { U4S8 t; t.v = v; return t.s; }

// Bit-exact 3-way bf16 split of 8 f32 (truncation; subtractions exact).
__device__ __forceinline__ void split3(const float4 a, const float4 b,
                                       short8& H, short8& M, short8& L) {
    const float f[8] = {a.x, a.y, a.z, a.w, b.x, b.y, b.z, b.w};
    U4S8 uh, um, ul;
#pragma unroll
    for (int p = 0; p < 4; ++p) {
        const float f0 = f[2 * p], f1 = f[2 * p + 1];
        const unsigned int t0 = __float_as_uint(f0) & 0xFFFF0000u;
        const unsigned int t1 = __float_as_uint(f1) & 0xFFFF0000u;
        uh.u[p] = (t0 >> 16) | t1;
        const float r0 = f0 - __uint_as_float(t0);
        const float r1 = f1 - __uint_as_float(t1);
        const unsigned int v0 = __float_as_uint(r0) & 0xFFFF0000u;
        const unsigned int v1 = __float_as_uint(r1) & 0xFFFF0000u;
        um.u[p] = (v0 >> 16) | v1;
        const float s0 = r0 - __uint_as_float(v0);
        const float s1 = r1 - __uint_as_float(v1);
        ul.u[p] = (__float_as_uint(s0) >> 16) | (__float_as_uint(s1) & 0xFFFF0000u);
    }
    H = uh.s; M = um.s; L = ul.s;
}

__device__ __forceinline__ f32x16 mfma6w(short8 ah, short8 am, short8 al,
                                         short8 bh, short8 bm, short8 bl,
                                         f32x16 c) {
    c = __builtin_amdgcn_mfma_f32_32x32x16_bf16(ah, bh, c, 0, 0, 0);
    c = __builtin_amdgcn_mfma_f32_32x32x16_bf16(ah, bm, c, 0, 0, 0);
    c = __builtin_amdgcn_mfma_f32_32x32x16_bf16(am, bh, c, 0, 0, 0);
    c = __builtin_amdgcn_mfma_f32_32x32x16_bf16(ah, bl, c, 0, 0, 0);
    c = __builtin_amdgcn_mfma_f32_32x32x16_bf16(am, bm, c, 0, 0, 0);
    c = __builtin_amdgcn_mfma_f32_32x32x16_bf16(al, bh, c, 0, 0, 0);
    return c;
}

// ---- pack W -> 32x32 B-fragment bf16 triples (HW-verified R5/R7/R8) ----
__global__ __launch_bounds__(64) void pack_w_kernel(
    const float* __restrict__ W, short* __restrict__ wpk)
{
    const int b  = blockIdx.x;          // 256 = c*8 + fg, fg = 2*s16 + n32
    const int c  = b >> 3, fg = b & 7;
    const int s  = fg >> 1, n32 = fg & 1;
    const int l  = threadIdx.x;
    const float* g = W + (size_t)(32 * n32 + (l & 31)) * DIMK
                       + 64 * c + 16 * s + 8 * (l >> 5);
    const float4 lo = *(const float4*)g;
    const float4 hi = *(const float4*)(g + 4);
    short8 H, M, L;
    split3(lo, hi, H, M, L);
    const size_t base = ((size_t)(c * 8 + fg) * 3) * 512 + l * 8;
    *(short8*)(wpk + base)        = H;
    *(short8*)(wpk + base + 512)  = M;
    *(short8*)(wpk + base + 1024) = L;
}

#define WLOAD3(d0, d1, d2, p)                                                 \
    asm volatile("global_load_dwordx4 %0, %3, off\n\t"                        \
                 "global_load_dwordx4 %1, %3, off offset:1024\n\t"            \
                 "global_load_dwordx4 %2, %3, off offset:2048"                \
                 : "=&v"(d0), "=&v"(d1), "=&v"(d2) : "v"(p))
#define WAITN(n) do {                                                         \
    asm volatile("s_waitcnt vmcnt(" #n ")" ::: "memory");                     \
    __builtin_amdgcn_sched_barrier(0);                                        \
} while (0)

__device__ __forceinline__ void async16(void* lds, const void* gp) {
    __builtin_amdgcn_global_load_lds(
        (const __attribute__((address_space(1))) unsigned int*)gp,
        (__attribute__((address_space(3))) unsigned int*)lds, 16, 0, 0);
}

// ================= R13 main: 128-token groups x 2 K-halves =================
__global__ __launch_bounds__(512, 1) void gate_half_kernel(
    const float* __restrict__ x, const short* __restrict__ wpk,
    float* __restrict__ pl)
{
    // 8 waves x 3 bufs x 4KB = 96KB wave-private staging; lg aliases it.
    __shared__ __align__(16) char smem[8 * 3 * 4096];

    const int tid = threadIdx.x;
    const int w   = tid >> 6;
    const int l   = tid & 63;
    const int r31 = l & 31;
    const int l5  = l >> 5;
    const int tw  = w >> 1;              // token sub-block 0..3
    const int kq2 = w & 1;               // K sub-quarter within half
    const int tgb = blockIdx.x >> 1;     // token group (128 tokens)
    const int kh  = blockIdx.x & 1;      // K half
    const int tok0 = tgb * 128 + tw * 32;
    const int q    = kh * 2 + kq2;       // global K quarter 0..3

    char* wbase = smem + w * 12288;
    const int swr = (r31 & 7) ^ (((r31 >> 3) & 3) << 1);
    const int srow = l >> 3;
    const int sg0  = (l & 7) ^ srow;
    const float* xrow0 = x + (size_t)(tok0 + srow) * DIMK + q * 512;

#define STAGE_CHUNK(k) do {                                                   \
    _Pragma("unroll")                                                         \
    for (int i = 0; i < 4; ++i) {                                             \
        const float* gsrc = xrow0 + (size_t)(8 * i) * DIMK + (k) * 32         \
                          + ((sg0 ^ (2 * i)) << 2);                           \
        async16(wbase + ((k) % 3) * 4096 + i * 1024, gsrc);                   \
    }                                                                         \
} while (0)

    // 4 tw-waves share this stream per kq2 (MSHR/L1 merge target)
    const short* wq0 = wpk + (size_t)q * 98304 + l * 8;
    const short* wq1 = wq0 + 1536;
    f32x16 acc0, acc1;
#pragma unroll
    for (int i = 0; i < 16; ++i) { acc0[i] = 0.f; acc1[i] = 0.f; }
    u32x4 w0v[4][3], w1v[4][3];

    STAGE_CHUNK(0); STAGE_CHUNK(1); STAGE_CHUNK(2);
    WLOAD3(w0v[0][0], w0v[0][1], w0v[0][2], wq0); wq0 += 3072;
    WLOAD3(w1v[0][0], w1v[0][1], w1v[0][2], wq1); wq1 += 3072;
    WLOAD3(w0v[1][0], w0v[1][1], w0v[1][2], wq0); wq0 += 3072;
    WLOAD3(w1v[1][0], w1v[1][1], w1v[1][2], wq1); wq1 += 3072;
    WLOAD3(w0v[2][0], w0v[2][1], w0v[2][2], wq0); wq0 += 3072;
    WLOAD3(w1v[2][0], w1v[2][1], w1v[2][2], wq1); wq1 += 3072;

    // R8's HW-proven schedule, verbatim literals (per-wave FIFO identical).
#define SLICE(t) do {                                                         \
    if ((t) <= 28) {                                                          \
        WLOAD3(w0v[((t)+3)&3][0], w0v[((t)+3)&3][1], w0v[((t)+3)&3][2], wq0); \
        wq0 += 3072;                                                          \
        WLOAD3(w1v[((t)+3)&3][0], w1v[((t)+3)&3][1], w1v[((t)+3)&3][2], wq1); \
        wq1 += 3072;                                                          \
    }                                                                         \
    if ((t) <= 1)            WAITN(18);                                       \
    else if ((t) == 29)      WAITN(12);                                       \
    else if ((t) == 30)      WAITN(6);                                        \
    else if ((t) == 31)      WAITN(0);                                        \
    else if (((t) & 1) || (t) == 2 || (t) == 28) WAITN(22);                   \
    else                     WAITN(26);                                       \
    {                                                                         \
        const char* xb = wbase + (((t) >> 1) % 3) * 4096;                     \
        const float4 a0 = *(const float4*)(xb + r31 * 128 +                   \
            (((((t) & 1) * 4 + 2 * l5 + 0) ^ swr) << 4));                     \
        const float4 a1 = *(const float4*)(xb + r31 * 128 +                   \
            (((((t) & 1) * 4 + 2 * l5 + 1) ^ swr) << 4));                     \
        short8 H, M, L;                                                       \
        split3(a0, a1, H, M, L);                                              \
        acc0 = mfma6w(H, M, L, as_s8(w0v[(t)&3][0]), as_s8(w0v[(t)&3][1]),    \
                      as_s8(w0v[(t)&3][2]), acc0);                            \
        acc1 = mfma6w(H, M, L, as_s8(w1v[(t)&3][0]), as_s8(w1v[(t)&3][1]),    \
                      as_s8(w1v[(t)&3][2]), acc1);                            \
    }                                                                         \
    if (((t) & 1) && (t) <= 25) STAGE_CHUNK(((t) + 5) >> 1);                  \
} while (0)

#define PBAR() __builtin_amdgcn_s_barrier()   // drift limiter (no LDS dep)

    SLICE(0);  SLICE(1);  SLICE(2);  SLICE(3);  PBAR();
    SLICE(4);  SLICE(5);  SLICE(6);  SLICE(7);  PBAR();
    SLICE(8);  SLICE(9);  SLICE(10); SLICE(11); PBAR();
    SLICE(12); SLICE(13); SLICE(14); SLICE(15); PBAR();
    SLICE(16); SLICE(17); SLICE(18); SLICE(19); PBAR();
    SLICE(20); SLICE(21); SLICE(22); SLICE(23); PBAR();
    SLICE(24); SLICE(25); SLICE(26); SLICE(27); PBAR();
    SLICE(28); SLICE(29); SLICE(30); SLICE(31);

    __syncthreads();   // staging reads done; lg aliases staging LDS

    // partials -> lg[w][32][65]; C/D: col=l&31, row=(r&3)+8*(r>>2)+4*l5
    float* lg = (float*)smem;
#pragma unroll
    for (int r = 0; r < 16; ++r) {
        const int rowc = (r & 3) + 8 * (r >> 2) + 4 * l5;
        lg[(w * 32 + rowc) * (NE + 1) + r31]      = acc0[r];
        lg[(w * 32 + rowc) * (NE + 1) + 32 + r31] = acc1[r];
    }
    __syncthreads();

    // in-block kq2-pair reduce -> pl[kh] plane (deterministic order)
#pragma unroll
    for (int rr = 0; rr < 16; ++rr) {
        const int idx = tid + rr * 512;          // 0..8191
        const int t5  = idx >> 6;                // token-in-block 0..127
        const int e   = idx & 63;
        const int tw2 = t5 >> 5, rloc = t5 & 31;
        const float s = lg[((2 * tw2) * 32 + rloc) * (NE + 1) + e]
                      + lg[((2 * tw2 + 1) * 32 + rloc) * (NE + 1) + e];
        pl[((size_t)kh * NT + tgb * 128 + t5) * NE + e] = s;
    }
#undef SLICE
#undef STAGE_CHUNK
#undef PBAR
}

// ========== combine: coalesced 2-way sum + softmax + top-8 ==========
__global__ __launch_bounds__(128) void gate_combine2_kernel(
    const float* __restrict__ pl, float* __restrict__ out)
{
    __shared__ float lgs[128][NE + 1];

    const int tid = threadIdx.x;
    const int t0  = blockIdx.x * 128;

#pragma unroll
    for (int i = 0; i < 16; ++i) {
        const int idx = i * 128 + tid;
        const int tok = idx >> 4, c4 = idx & 15;
        const size_t off = ((size_t)t0 + tok) * NE + c4 * 4;
        const f32x4 v0 = *(const f32x4*)(pl + off);
        const f32x4 v1 = *(const f32x4*)(pl + (size_t)NT * NE + off);
        const f32x4 s = v0 + v1;
#pragma unroll
        for (int j = 0; j < 4; ++j) lgs[tok][c4 * 4 + j] = s[j];
    }
    __syncthreads();

    const float* rowp = &lgs[tid][0];
    float mx = -3.402823466e38f;
    for (int e = 0; e < NE; ++e) mx = fmaxf(mx, rowp[e]);
    float sden = 0.f;
    for (int e = 0; e < NE; ++e) sden += expf(rowp[e] - mx);

    float tv[TOPKK];
    int   ti[TOPKK];
#pragma unroll
    for (int i = 0; i < TOPKK; ++i) { tv[i] = -3.402823466e38f; ti[i] = 0; }
    for (int e = 0; e < NE; ++e) {
        const float v = rowp[e];
        if (v > tv[TOPKK - 1]) {
            tv[TOPKK - 1] = v; ti[TOPKK - 1] = e;
#pragma unroll
            for (int q = TOPKK - 1; q > 0; --q) {
                if (tv[q] > tv[q - 1]) {
                    const float fv = tv[q]; tv[q] = tv[q - 1]; tv[q - 1] = fv;
                    const int   iv = ti[q]; ti[q] = ti[q - 1]; ti[q - 1] = iv;
                }
            }
        }
    }

    float* ow = out + (size_t)(t0 + tid) * TOPKK;
    float* oi = out + (size_t)NT * TOPKK + (size_t)(t0 + tid) * TOPKK;
#pragma unroll
    for (int i = 0; i < TOPKK; ++i) {
        ow[i] = expf(tv[i] - mx) / sden;   // ROUTE_SCALE == 1.0
        oi[i] = (float)ti[i];
    }
}

// ================= R12 main (fallback if ws < WS_NEED) =================
__global__ __launch_bounds__(256, 2) void gate_main_r12(
    const float* __restrict__ x, const short* __restrict__ wpk,
    float* __restrict__ out)
{
    __shared__ __align__(16) char smem[4 * 3 * 4096];
    const int tid = threadIdx.x;
    const int w   = tid >> 6;
    const int l   = tid & 63;
    const int r31 = l & 31;
    const int l5  = l >> 5;
    const int kq  = w;
    const int bt0 = blockIdx.x * 32;
    char* wbase = smem + w * 12288;
    const int swr = (r31 & 7) ^ (((r31 >> 3) & 3) << 1);
    const int srow = l >> 3;
    const int sg0  = (l & 7) ^ srow;
    const float* xrow0 = x + (size_t)(bt0 + srow) * DIMK + kq * 512;

#define STAGE_CHUNK(k) do {                                                   \
    _Pragma("unroll")                                                         \
    for (int i = 0; i < 4; ++i) {                                             \
        const float* gsrc = xrow0 + (size_t)(8 * i) * DIMK + (k) * 32         \
                          + ((sg0 ^ (2 * i)) << 2);                           \
        async16(wbase + ((k) % 3) * 4096 + i * 1024, gsrc);                   \
    }                                                                         \
} while (0)

    const short* wq0 = wpk + (size_t)kq * 98304 + l * 8;
    const short* wq1 = wq0 + 1536;
    f32x16 acc0, acc1;
#pragma unroll
    for (int i = 0; i < 16; ++i) { acc0[i] = 0.f; acc1[i] = 0.f; }
    u32x4 w0v[4][3], w1v[4][3];
    STAGE_CHUNK(0); STAGE_CHUNK(1); STAGE_CHUNK(2);
    WLOAD3(w0v[0][0], w0v[0][1], w0v[0][2], wq0); wq0 += 3072;
    WLOAD3(w1v[0][0], w1v[0][1], w1v[0][2], wq1); wq1 += 3072;
    WLOAD3(w0v[1][0], w0v[1][1], w0v[1][2], wq0); wq0 += 3072;
    WLOAD3(w1v[1][0], w1v[1][1], w1v[1][2], wq1); wq1 += 3072;
    WLOAD3(w0v[2][0], w0v[2][1], w0v[2][2], wq0); wq0 += 3072;
    WLOAD3(w1v[2][0], w1v[2][1], w1v[2][2], wq1); wq1 += 3072;

#define SLICE(t) do {                                                         \
    if ((t) <= 28) {                                                          \
        WLOAD3(w0v[((t)+3)&3][0], w0v[((t)+3)&3][1], w0v[((t)+3)&3][2], wq0); \
        wq0 += 3072;                                                          \
        WLOAD3(w1v[((t)+3)&3][0], w1v[((t)+3)&3][1], w1v[((t)+3)&3][2], wq1); \
        wq1 += 3072;                                                          \
    }                                                                         \
    if ((t) <= 1)            WAITN(18);                                       \
    else if ((t) == 29)      WAITN(12);                                       \
    else if ((t) == 30)      WAITN(6);                                        \
    else if ((t) == 31)      WAITN(0);                                        \
    else if (((t) & 1) || (t) == 2 || (t) == 28) WAITN(22);                   \
    else                     WAITN(26);                                       \
    {                                                                         \
        const char* xb = wbase + (((t) >> 1) % 3) * 4096;                     \
        const float4 a0 = *(const float4*)(xb + r31 * 128 +                   \
            (((((t) & 1) * 4 + 2 * l5 + 0) ^ swr) << 4));                     \
        const float4 a1 = *(const float4*)(xb + r31 * 128 +                   \
            (((((t) & 1) * 4 + 2 * l5 + 1) ^ swr) << 4));                     \
        short8 H, M, L;                                                       \
        split3(a0, a1, H, M, L);                                              \
        acc0 = mfma6w(H, M, L, as_s8(w0v[(t)&3][0]), as_s8(w0v[(t)&3][1]),    \
                      as_s8(w0v[(t)&3][2]), acc0);                            \
        acc1 = mfma6w(H, M, L, as_s8(w1v[(t)&3][0]), as_s8(w1v[(t)&3][1]),    \
                      as_s8(w1v[(t)&3][2]), acc1);                            \
    }                                                                         \
    if (((t) & 1) && (t) <= 25) STAGE_CHUNK(((t) + 5) >> 1);                  \
} while (0)

    SLICE(0);  SLICE(1);  SLICE(2);  SLICE(3);
    SLICE(4);  SLICE(5);  SLICE(6);  SLICE(7);
    SLICE(8);  SLICE(9);  SLICE(10); SLICE(11);
    SLICE(12); SLICE(13); SLICE(14); SLICE(15);
    SLICE(16); SLICE(17); SLICE(18); SLICE(19);
    SLICE(20); SLICE(21); SLICE(22); SLICE(23);
    SLICE(24); SLICE(25); SLICE(26); SLICE(27);
    SLICE(28); SLICE(29); SLICE(30); SLICE(31);

    __syncthreads();
    float* lg = (float*)smem;
#pragma unroll
    for (int r = 0; r < 16; ++r) {
        const int rowc = (r & 3) + 8 * (r >> 2) + 4 * l5;
        lg[(w * 32 + rowc) * (NE + 1) + r31]      = acc0[r];
        lg[(w * 32 + rowc) * (NE + 1) + 32 + r31] = acc1[r];
    }
    __syncthreads();
#pragma unroll
    for (int rr = 0; rr < 8; ++rr) {
        const int idx = tid + rr * 256;
        const int t = idx >> 6, e = idx & 63;
        lg[t * (NE + 1) + e] =
            (lg[t * (NE + 1) + e] + lg[(32 + t) * (NE + 1) + e]) +
            (lg[(64 + t) * (NE + 1) + e] + lg[(96 + t) * (NE + 1) + e]);
    }
    __syncthreads();
    if (tid < 32) {
        const float* rowp = lg + tid * (NE + 1);
        float mx = -3.402823466e38f;
        for (int e = 0; e < NE; ++e) mx = fmaxf(mx, rowp[e]);
        float sden = 0.f;
        for (int e = 0; e < NE; ++e) sden += expf(rowp[e] - mx);
        float tv[TOPKK]; int ti[TOPKK];
#pragma unroll
        for (int i = 0; i < TOPKK; ++i) { tv[i] = -3.402823466e38f; ti[i] = 0; }
        for (int e = 0; e < NE; ++e) {
            const float v = rowp[e];
            if (v > tv[TOPKK - 1]) {
                tv[TOPKK - 1] = v; ti[TOPKK - 1] = e;
#pragma unroll
                for (int q = TOPKK - 1; q > 0; --q) {
                    if (tv[q] > tv[q - 1]) {
                        const float fv = tv[q]; tv[q] = tv[q - 1]; tv[q - 1] = fv;
                        const int   iv = ti[q]; ti[q] = ti[q - 1]; ti[q - 1] = iv;
                    }
                }
            }
        }
        float* ow = out + (size_t)(bt0 + tid) * TOPKK;
        float* oi = out + (size_t)NT * TOPKK + (size_t)(bt0 + tid) * TOPKK;
#pragma unroll
        for (int i = 0; i < TOPKK; ++i) {
            ow[i] = expf(tv[i] - mx) / sden;
            oi[i] = (float)ti[i];
        }
    }
#undef SLICE
#undef STAGE_CHUNK
}

extern "C" void kernel_launch(void* const* d_in, const int* in_sizes, int n_in,
                              void* d_out, int out_size, void* d_ws, size_t ws_size,
                              hipStream_t stream) {
    const float* x = (const float*)d_in[0];
    const float* W = (const float*)d_in[1];
    float* out = (float*)d_out;
    short* wpk = (short*)d_ws;
    if (ws_size >= (size_t)WS_NEED) {
        float* pl = (float*)((char*)d_ws + WPK_BYTES);
        hipLaunchKernelGGL(pack_w_kernel, dim3(256), dim3(64), 0, stream, W, wpk);
        hipLaunchKernelGGL(gate_half_kernel, dim3(256), dim3(512), 0, stream,
                           x, wpk, pl);
        hipLaunchKernelGGL(gate_combine2_kernel, dim3(NT / 128), dim3(128), 0,
                           stream, pl, out);
    } else if (ws_size >= (size_t)WPK_BYTES) {
        hipLaunchKernelGGL(pack_w_kernel, dim3(256), dim3(64), 0, stream, W, wpk);
        hipLaunchKernelGGL(gate_main_r12, dim3(NT / 32), dim3(256), 0, stream,
                           x, wpk, out);
    }
}

// Round 14
// 55.576 us; speedup vs baseline: 1.0268x; 1.0268x over previous
//
#include <hip/hip_runtime.h>

// MoE gate: logits = x @ W^T (x:[16384,2048] f32, W:[64,2048] f32),
// softmax over 64 experts, top-8 -> weights f32 + indices stored as f32.
//
// R14: R8's HW-proven barrier-free design with W as f32 fragment-pack.
//  pack_wf: W f32 -> fragment-ordered f32 (512KB, lane-contiguous) -- 33%
//           fewer W bytes than the bf16-triple pack (768KB). split3 of W
//           moves on-the-fly into the main kernel (~2 split3/slice VALU,
//           hidden: VALUBusy was 9%).
//  main:    grid 256, 512thr = 8 waves (2 tw x 4 kq); wave = 32tok x 64exp
//           x 512K. R8's SLICE schedule verbatim; W FIFO re-derived for
//           4 loads/slice: waits 12/16/20, tails 16/8/4/0 (slice-audited).
//           x: wave-private 3-deep LDS staging (granule-XOR both sides).
//           NO barriers in K-loop; in-block 4-way combine + softmax/top-8.
// Per-CU traffic: x 512KB + W 512KB = 1.0MB (R8: 1.25MB).

typedef __attribute__((ext_vector_type(8))) short short8;
typedef __attribute__((ext_vector_type(16))) float f32x16;
typedef __attribute__((ext_vector_type(4))) float f32x4;

#define NT    16384
#define DIMK  2048
#define NE    64
#define TOPKK 8
#define TT    64
#define WF_BYTES 524288   // 4 q x 32 s x 2 n32 x 512 f32

union U4S8 { unsigned int u[4]; short8 s; };

// Bit-exact 3-way bf16 split of 8 f32 (truncation; subtractions exact).
__device__ __forceinline__ void split3(const float4 a, const float4 b,
                                       short8& H, short8& M, short8& L) {
    const float f[8] = {a.x, a.y, a.z, a.w, b.x, b.y, b.z, b.w};
    U4S8 uh, um, ul;
#pragma unroll
    for (int p = 0; p < 4; ++p) {
        const float f0 = f[2 * p], f1 = f[2 * p + 1];
        const unsigned int t0 = __float_as_uint(f0) & 0xFFFF0000u;
        const unsigned int t1 = __float_as_uint(f1) & 0xFFFF0000u;
        uh.u[p] = (t0 >> 16) | t1;
        const float r0 = f0 - __uint_as_float(t0);
        const float r1 = f1 - __uint_as_float(t1);
        const unsigned int v0 = __float_as_uint(r0) & 0xFFFF0000u;
        const unsigned int v1 = __float_as_uint(r1) & 0xFFFF0000u;
        um.u[p] = (v0 >> 16) | v1;
        const float s0 = r0 - __uint_as_float(v0);
        const float s1 = r1 - __uint_as_float(v1);
        ul.u[p] = (__float_as_uint(s0) >> 16) | (__float_as_uint(s1) & 0xFFFF0000u);
    }
    H = uh.s; M = um.s; L = ul.s;
}

__device__ __forceinline__ f32x16 mfma6w(short8 ah, short8 am, short8 al,
                                         short8 bh, short8 bm, short8 bl,
                                         f32x16 c) {
    c = __builtin_amdgcn_mfma_f32_32x32x16_bf16(ah, bh, c, 0, 0, 0);
    c = __builtin_amdgcn_mfma_f32_32x32x16_bf16(ah, bm, c, 0, 0, 0);
    c = __builtin_amdgcn_mfma_f32_32x32x16_bf16(am, bh, c, 0, 0, 0);
    c = __builtin_amdgcn_mfma_f32_32x32x16_bf16(ah, bl, c, 0, 0, 0);
    c = __builtin_amdgcn_mfma_f32_32x32x16_bf16(am, bm, c, 0, 0, 0);
    c = __builtin_amdgcn_mfma_f32_32x32x16_bf16(al, bh, c, 0, 0, 0);
    return c;
}

// ---- pack W -> fragment-ordered f32 (B-fragment layout, HW-verified) ----
// wf[((q*32 + s)*2 + n32)*512 + l*8 + j] = W[32*n32 + (l&31)]
//                                           [q*512 + s*16 + 8*(l>>5) + j]
__global__ __launch_bounds__(64) void pack_wf_kernel(
    const float* __restrict__ W, float* __restrict__ wf)
{
    const int b   = blockIdx.x;          // 256 = ((q*32)+s)*2 + n32
    const int n32 = b & 1;
    const int s   = (b >> 1) & 31;
    const int q   = b >> 6;
    const int l   = threadIdx.x;
    const float* g = W + (size_t)(32 * n32 + (l & 31)) * DIMK
                       + q * 512 + s * 16 + 8 * (l >> 5);
    const float4 lo = *(const float4*)g;
    const float4 hi = *(const float4*)(g + 4);
    float* d = wf + (size_t)b * 512 + l * 8;
    *(float4*)d       = lo;
    *(float4*)(d + 4) = hi;
}

// W slice load: 4 x dwordx4 = n32={0,1} x 8 f32; frag n32=1 at +2048B.
#define WLOADF(a0, b0, a1, b1, p)                                             \
    asm volatile("global_load_dwordx4 %0, %4, off\n\t"                        \
                 "global_load_dwordx4 %1, %4, off offset:16\n\t"              \
                 "global_load_dwordx4 %2, %4, off offset:2048\n\t"            \
                 "global_load_dwordx4 %3, %4, off offset:2064"                \
                 : "=&v"(a0), "=&v"(b0), "=&v"(a1), "=&v"(b1) : "v"(p))
#define WAITN(n) do {                                                         \
    asm volatile("s_waitcnt vmcnt(" #n ")" ::: "memory");                     \
    __builtin_amdgcn_sched_barrier(0);                                        \
} while (0)

__device__ __forceinline__ void async16(void* lds, const void* gp) {
    __builtin_amdgcn_global_load_lds(
        (const __attribute__((address_space(1))) unsigned int*)gp,
        (__attribute__((address_space(3))) unsigned int*)lds, 16, 0, 0);
}

// ================= R14 main =================
__global__ __launch_bounds__(512, 1) void gate_main_r14(
    const float* __restrict__ x, const float* __restrict__ wf,
    float* __restrict__ out)
{
    // 8 waves x 3 bufs x 4KB = 96KB wave-private staging; lg aliases it.
    __shared__ __align__(16) char smem[8 * 3 * 4096];

    const int tid = threadIdx.x;
    const int w   = tid >> 6;
    const int l   = tid & 63;
    const int r31 = l & 31;
    const int l5  = l >> 5;
    const int tw  = w & 1;          // token half (32 tokens)
    const int kq  = w >> 1;         // K quarter
    const int bt0 = blockIdx.x * TT;

    char* wbase = smem + w * 12288;
    const int swr = (r31 & 7) ^ (((r31 >> 3) & 3) << 1);
    const int srow = l >> 3;
    const int sg0  = (l & 7) ^ srow;
    const float* xrow0 = x + (size_t)(bt0 + 32 * tw + srow) * DIMK + kq * 512;

#define STAGE_CHUNK(k) do {                                                   \
    _Pragma("unroll")                                                         \
    for (int i = 0; i < 4; ++i) {                                             \
        const float* gsrc = xrow0 + (size_t)(8 * i) * DIMK + (k) * 32         \
                          + ((sg0 ^ (2 * i)) << 2);                           \
        async16(wbase + ((k) % 3) * 4096 + i * 1024, gsrc);                   \
    }                                                                         \
} while (0)

    // W f32 fragment stream: wave quarter kq; advance 1024 f32 per slice.
    const float* wq = wf + (size_t)kq * 32768 + l * 8;

    f32x16 acc0, acc1;
#pragma unroll
    for (int i = 0; i < 16; ++i) { acc0[i] = 0.f; acc1[i] = 0.f; }
    float4 w0a[4], w0b[4], w1a[4], w1b[4];   // 4-bank W ring (f32)

    STAGE_CHUNK(0); STAGE_CHUNK(1); STAGE_CHUNK(2);
    WLOADF(w0a[0], w0b[0], w1a[0], w1b[0], wq); wq += 1024;
    WLOADF(w0a[1], w0b[1], w1a[1], w1b[1], wq); wq += 1024;
    WLOADF(w0a[2], w0b[2], w1a[2], w1b[2], wq); wq += 1024;

    // R8's schedule; W FIFO re-derived for 4 loads/slice (slice-audited):
    // t<=1:12; t==29:8; t==30:4; t==31:0; odd||t==2||t==28:16; else 20.
#define SLICE(t) do {                                                         \
    if ((t) <= 28) {                                                          \
        WLOADF(w0a[((t)+3)&3], w0b[((t)+3)&3],                                \
               w1a[((t)+3)&3], w1b[((t)+3)&3], wq);                           \
        wq += 1024;                                                           \
    }                                                                         \
    if ((t) <= 1)            WAITN(12);                                       \
    else if ((t) == 29)      WAITN(8);                                        \
    else if ((t) == 30)      WAITN(4);                                        \
    else if ((t) == 31)      WAITN(0);                                        \
    else if (((t) & 1) || (t) == 2 || (t) == 28) WAITN(16);                   \
    else                     WAITN(20);                                       \
    {                                                                         \
        const char* xb = wbase + (((t) >> 1) % 3) * 4096;                     \
        const float4 a0 = *(const float4*)(xb + r31 * 128 +                   \
            (((((t) & 1) * 4 + 2 * l5 + 0) ^ swr) << 4));                     \
        const float4 a1 = *(const float4*)(xb + r31 * 128 +                   \
            (((((t) & 1) * 4 + 2 * l5 + 1) ^ swr) << 4));                     \
        short8 H, M, L;                                                       \
        split3(a0, a1, H, M, L);                                              \
        short8 BH, BM, BL;                                                    \
        split3(w0a[(t)&3], w0b[(t)&3], BH, BM, BL);                           \
        acc0 = mfma6w(H, M, L, BH, BM, BL, acc0);                             \
        split3(w1a[(t)&3], w1b[(t)&3], BH, BM, BL);                           \
        acc1 = mfma6w(H, M, L, BH, BM, BL, acc1);                             \
    }                                                                         \
    if (((t) & 1) && (t) <= 25) STAGE_CHUNK(((t) + 5) >> 1);                  \
} while (0)

    SLICE(0);  SLICE(1);  SLICE(2);  SLICE(3);
    SLICE(4);  SLICE(5);  SLICE(6);  SLICE(7);
    SLICE(8);  SLICE(9);  SLICE(10); SLICE(11);
    SLICE(12); SLICE(13); SLICE(14); SLICE(15);
    SLICE(16); SLICE(17); SLICE(18); SLICE(19);
    SLICE(20); SLICE(21); SLICE(22); SLICE(23);
    SLICE(24); SLICE(25); SLICE(26); SLICE(27);
    SLICE(28); SLICE(29); SLICE(30); SLICE(31);

    __syncthreads();   // staging reads done; lg aliases staging LDS

    // partials -> lg[kq][64][65]; C/D: col=l&31, row=(r&3)+8*(r>>2)+4*l5
    float* lg = (float*)smem;
#pragma unroll
    for (int r = 0; r < 16; ++r) {
        const int rowc = (r & 3) + 8 * (r >> 2) + 4 * l5;
        const int trow = 32 * tw + rowc;
        lg[(kq * TT + trow) * (NE + 1) + r31]      = acc0[r];
        lg[(kq * TT + trow) * (NE + 1) + 32 + r31] = acc1[r];
    }
    __syncthreads();

    // deterministic 4-way K reduction: 4096 entries / 512 thr
#pragma unroll
    for (int rr = 0; rr < (TT * NE) / 512; ++rr) {
        const int idx = tid + rr * 512;
        const int t = idx >> 6, e = idx & 63;
        lg[t * (NE + 1) + e] =
            (lg[t * (NE + 1) + e] + lg[(TT + t) * (NE + 1) + e]) +
            (lg[(2 * TT + t) * (NE + 1) + e] + lg[(3 * TT + t) * (NE + 1) + e]);
    }
    __syncthreads();

    // fused softmax + top-8: one lane per token
    if (tid < TT) {
        const float* rowp = lg + tid * (NE + 1);
        float mx = -3.402823466e38f;
        for (int e = 0; e < NE; ++e) mx = fmaxf(mx, rowp[e]);
        float sden = 0.f;
        for (int e = 0; e < NE; ++e) sden += expf(rowp[e] - mx);

        float tv[TOPKK];
        int   ti[TOPKK];
#pragma unroll
        for (int i = 0; i < TOPKK; ++i) { tv[i] = -3.402823466e38f; ti[i] = 0; }
        for (int e = 0; e < NE; ++e) {
            const float v = rowp[e];
            if (v > tv[TOPKK - 1]) {
                tv[TOPKK - 1] = v; ti[TOPKK - 1] = e;
#pragma unroll
                for (int q = TOPKK - 1; q > 0; --q) {
                    if (tv[q] > tv[q - 1]) {
                        const float fv = tv[q]; tv[q] = tv[q - 1]; tv[q - 1] = fv;
                        const int   iv = ti[q]; ti[q] = ti[q - 1]; ti[q - 1] = iv;
                    }
                }
            }
        }
        float* ow = out + (size_t)(bt0 + tid) * TOPKK;
        float* oi = out + (size_t)NT * TOPKK + (size_t)(bt0 + tid) * TOPKK;
#pragma unroll
        for (int i = 0; i < TOPKK; ++i) {
            ow[i] = expf(tv[i] - mx) / sden;   // ROUTE_SCALE == 1.0
            oi[i] = (float)ti[i];
        }
    }
#undef SLICE
#undef STAGE_CHUNK
}

// ================= fallback (no-ws): R2-style reg-direct kernel ===========
__device__ __forceinline__ f32x4 mfma6s(short8 ah, short8 am, short8 al,
                                        short8 bh, short8 bm, short8 bl, f32x4 c) {
    c = __builtin_amdgcn_mfma_f32_16x16x32_bf16(ah, bh, c, 0, 0, 0);
    c = __builtin_amdgcn_mfma_f32_16x16x32_bf16(ah, bm, c, 0, 0, 0);
    c = __builtin_amdgcn_mfma_f32_16x16x32_bf16(am, bh, c, 0, 0, 0);
    c = __builtin_amdgcn_mfma_f32_16x16x32_bf16(ah, bl, c, 0, 0, 0);
    c = __builtin_amdgcn_mfma_f32_16x16x32_bf16(am, bm, c, 0, 0, 0);
    c = __builtin_amdgcn_mfma_f32_16x16x32_bf16(al, bh, c, 0, 0, 0);
    return c;
}

__device__ __forceinline__ void load_step(const float* xp0, const float* xp1,
                                          const float* wp, int koff,
                                          float4 xb[2][2], float4 wb[4][2]) {
#pragma unroll
    for (int h = 0; h < 2; ++h) {
        xb[0][h] = *(const float4*)(xp0 + koff + 4 * h);
        xb[1][h] = *(const float4*)(xp1 + koff + 4 * h);
    }
#pragma unroll
    for (int n = 0; n < 4; ++n)
#pragma unroll
        for (int h = 0; h < 2; ++h)
            wb[n][h] = *(const float4*)(wp + (size_t)n * 16 * DIMK + koff + 4 * h);
}

__device__ __forceinline__ void do_step(const float4 xc[2][2], const float4 wc[4][2],
                                        f32x4 acc[2][4]) {
    short8 ah[2], am[2], al[2];
#pragma unroll
    for (int m = 0; m < 2; ++m) split3(xc[m][0], xc[m][1], ah[m], am[m], al[m]);
#pragma unroll
    for (int n = 0; n < 4; ++n) {
        short8 bh, bm, bl;
        split3(wc[n][0], wc[n][1], bh, bm, bl);
#pragma unroll
        for (int m = 0; m < 2; ++m)
            acc[m][n] = mfma6s(ah[m], am[m], al[m], bh, bm, bl, acc[m][n]);
    }
}

__global__ __launch_bounds__(256, 2) void gate_fallback_kernel(
    const float* __restrict__ x, const float* __restrict__ W,
    float* __restrict__ out)
{
    __shared__ float lg[4][32][NE + 1];
    const int tid = threadIdx.x;
    const int w = tid >> 6, l = tid & 63;
    const int j = l & 15, g = l >> 4;
    const int bt0 = blockIdx.x * 32;
    const int kb = w * 512;
    const float* xp0 = x + (size_t)(bt0 + j) * DIMK + kb + 8 * g;
    const float* xp1 = xp0 + (size_t)16 * DIMK;
    const float* wpp = W + (size_t)j * DIMK + kb + 8 * g;
    f32x4 acc[2][4];
#pragma unroll
    for (int m = 0; m < 2; ++m)
#pragma unroll
        for (int n = 0; n < 4; ++n) acc[m][n] = (f32x4){0.f, 0.f, 0.f, 0.f};
    float4 xA[2][2], wA[4][2], xB[2][2], wB[4][2];
    load_step(xp0, xp1, wpp, 0, xA, wA);
#pragma unroll 1
    for (int s = 0; s < 16; s += 2) {
        load_step(xp0, xp1, wpp, 32 * (s + 1), xB, wB);
        do_step(xA, wA, acc);
        if (s + 2 < 16) load_step(xp0, xp1, wpp, 32 * (s + 2), xA, wA);
        do_step(xB, wB, acc);
    }
#pragma unroll
    for (int m = 0; m < 2; ++m)
#pragma unroll
        for (int n = 0; n < 4; ++n)
#pragma unroll
            for (int q = 0; q < 4; ++q)
                lg[w][16 * m + 4 * g + q][16 * n + j] = acc[m][n][q];
    __syncthreads();
#pragma unroll
    for (int r = 0; r < 8; ++r) {
        const int idx = tid + r * 256;
        const int t = idx >> 6, e = idx & 63;
        lg[0][t][e] += lg[1][t][e] + lg[2][t][e] + lg[3][t][e];
    }
    __syncthreads();
    if (tid < 32) {
        const float* rowp = &lg[0][tid][0];
        float mx = -3.402823466e38f;
        for (int e = 0; e < NE; ++e) mx = fmaxf(mx, rowp[e]);
        float sden = 0.f;
        for (int e = 0; e < NE; ++e) sden += expf(rowp[e] - mx);
        float tv[TOPKK]; int ti[TOPKK];
#pragma unroll
        for (int i = 0; i < TOPKK; ++i) { tv[i] = -3.402823466e38f; ti[i] = 0; }
        for (int e = 0; e < NE; ++e) {
            const float v = rowp[e];
            if (v > tv[TOPKK - 1]) {
                tv[TOPKK - 1] = v; ti[TOPKK - 1] = e;
#pragma unroll
                for (int q = TOPKK - 1; q > 0; --q)
                    if (tv[q] > tv[q - 1]) {
                        const float fv = tv[q]; tv[q] = tv[q - 1]; tv[q - 1] = fv;
                        const int iv = ti[q]; ti[q] = ti[q - 1]; ti[q - 1] = iv;
                    }
            }
        }
        float* ow = out + (size_t)(bt0 + tid) * TOPKK;
        float* oi = out + (size_t)NT * TOPKK + (size_t)(bt0 + tid) * TOPKK;
#pragma unroll
        for (int i = 0; i < TOPKK; ++i) {
            ow[i] = expf(tv[i] - mx) / sden;
            oi[i] = (float)ti[i];
        }
    }
}

extern "C" void kernel_launch(void* const* d_in, const int* in_sizes, int n_in,
                              void* d_out, int out_size, void* d_ws, size_t ws_size,
                              hipStream_t stream) {
    const float* x = (const float*)d_in[0];
    const float* W = (const float*)d_in[1];
    float* out = (float*)d_out;
    if (ws_size >= (size_t)WF_BYTES) {
        float* wf = (float*)d_ws;
        hipLaunchKernelGGL(pack_wf_kernel, dim3(256), dim3(64), 0, stream, W, wf);
        hipLaunchKernelGGL(gate_main_r14, dim3(NT / TT), dim3(512), 0, stream,
                           x, wf, out);
    } else {
        hipLaunchKernelGGL(gate_fallback_kernel, dim3(NT / 32), dim3(256), 0, stream,
                           x, W, out);
    }
}

// Round 15
// 51.623 us; speedup vs baseline: 1.1055x; 1.0766x over previous
//
#include <hip/hip_runtime.h>

// MoE gate: logits = x @ W^T (x:[16384,2048] f32, W:[64,2048] f32),
// softmax over 64 experts, top-8 -> weights f32 + indices stored as f32.
//
// R15 = R8 verbatim (best measured: 51.6 us). Barrier-free reg GEMM +
// wave-private LDS x-staging:
//  - grid 256 (1 block/CU), 512 thr = 8 waves; wave = 32tok x 64exp x K/4.
//  - x: 3-deep wave-private LDS chunks (32tok x 32k = 4KB), staged with 4
//    contiguous global_load_lds (128B runs), granule-XOR pre-swizzled source
//    + matching XOR ds_read. NO s_barrier in K-loop.
//  - W: packed bf16 H/M/L triples (768KB, L2-hot), register depth-3 slices
//    (4 banks), FIFO-audited literal vmcnt per slice.
//  - mfma_f32_32x32x16_bf16, 6-product exact split ~= fp32 (HW-verified).

typedef __attribute__((ext_vector_type(8))) short short8;
typedef __attribute__((ext_vector_type(16))) float f32x16;
typedef __attribute__((ext_vector_type(4))) float f32x4;
typedef __attribute__((ext_vector_type(4))) unsigned int u32x4;

#define NT    16384
#define DIMK  2048
#define NE    64
#define TOPKK 8
#define TT    64
#define WS_BYTES (32 * 24 * 1024)   // 786432

union U4S8 { unsigned int u[4]; short8 s; u32x4 v; };

__device__ __forceinline__ short8 as_s8(u32x4 v) { U4S8 t; t.v = v; return t.s; }

// Bit-exact 3-way bf16 split of 8 f32 (truncation; subtractions exact).
__device__ __forceinline__ void split3(const float4 a, const float4 b,
                                       short8& H, short8& M, short8& L) {
    const float f[8] = {a.x, a.y, a.z, a.w, b.x, b.y, b.z, b.w};
    U4S8 uh, um, ul;
#pragma unroll
    for (int p = 0; p < 4; ++p) {
        const float f0 = f[2 * p], f1 = f[2 * p + 1];
        const unsigned int t0 = __float_as_uint(f0) & 0xFFFF0000u;
        const unsigned int t1 = __float_as_uint(f1) & 0xFFFF0000u;
        uh.u[p] = (t0 >> 16) | t1;
        const float r0 = f0 - __uint_as_float(t0);
        const float r1 = f1 - __uint_as_float(t1);
        const unsigned int v0 = __float_as_uint(r0) & 0xFFFF0000u;
        const unsigned int v1 = __float_as_uint(r1) & 0xFFFF0000u;
        um.u[p] = (v0 >> 16) | v1;
        const float s0 = r0 - __uint_as_float(v0);
        const float s1 = r1 - __uint_as_float(v1);
        ul.u[p] = (__float_as_uint(s0) >> 16) | (__float_as_uint(s1) & 0xFFFF0000u);
    }
    H = uh.s; M = um.s; L = ul.s;
}

__device__ __forceinline__ f32x16 mfma6w(short8 ah, short8 am, short8 al,
                                         short8 bh, short8 bm, short8 bl,
                                         f32x16 c) {
    c = __builtin_amdgcn_mfma_f32_32x32x16_bf16(ah, bh, c, 0, 0, 0);
    c = __builtin_amdgcn_mfma_f32_32x32x16_bf16(ah, bm, c, 0, 0, 0);
    c = __builtin_amdgcn_mfma_f32_32x32x16_bf16(am, bh, c, 0, 0, 0);
    c = __builtin_amdgcn_mfma_f32_32x32x16_bf16(ah, bl, c, 0, 0, 0);
    c = __builtin_amdgcn_mfma_f32_32x32x16_bf16(am, bm, c, 0, 0, 0);
    c = __builtin_amdgcn_mfma_f32_32x32x16_bf16(al, bh, c, 0, 0, 0);
    return c;
}

// ---- pack W -> 32x32 B-fragment-ordered bf16 triples (verified R5/R7) ----
// ws: [c64(32)][fg(8)][t(3)][512 shorts]; fg = 2*s16 + n32;
// lane l: expert = 32*n32 + (l&31), k = 64c + 16*s16 + 8*(l>>5) + 0..7.
__global__ __launch_bounds__(64) void pack_w_kernel(
    const float* __restrict__ W, short* __restrict__ wpk)
{
    const int b  = blockIdx.x;          // 256 = c*8 + fg
    const int c  = b >> 3, fg = b & 7;
    const int s  = fg >> 1, n32 = fg & 1;
    const int l  = threadIdx.x;
    const float* g = W + (size_t)(32 * n32 + (l & 31)) * DIMK
                       + 64 * c + 16 * s + 8 * (l >> 5);
    const float4 lo = *(const float4*)g;
    const float4 hi = *(const float4*)(g + 4);
    short8 H, M, L;
    split3(lo, hi, H, M, L);
    const size_t base = ((size_t)c * 24 + (s * 4 + n32 * 0 + fg - 2 * s - n32) * 0
                         + (c * 0)) * 0 + ((size_t)(c * 8 + fg) * 3) * 512 + l * 8;
    *(short8*)(wpk + base)        = H;
    *(short8*)(wpk + base + 512)  = M;
    *(short8*)(wpk + base + 1024) = L;
}

// Inline-asm W loads: issue only; ordering by manual counted vmcnt.
#define WLOAD3(d0, d1, d2, p)                                                 \
    asm volatile("global_load_dwordx4 %0, %3, off\n\t"                        \
                 "global_load_dwordx4 %1, %3, off offset:1024\n\t"            \
                 "global_load_dwordx4 %2, %3, off offset:2048"                \
                 : "=&v"(d0), "=&v"(d1), "=&v"(d2) : "v"(p))
#define WAITN(n) do {                                                         \
    asm volatile("s_waitcnt vmcnt(" #n ")" ::: "memory");                     \
    __builtin_amdgcn_sched_barrier(0);                                        \
} while (0)

__device__ __forceinline__ void async16(void* lds, const void* gp) {
    __builtin_amdgcn_global_load_lds(
        (const __attribute__((address_space(1))) unsigned int*)gp,
        (__attribute__((address_space(3))) unsigned int*)lds, 16, 0, 0);
}

// ---- main fused kernel (R8 verbatim) ----
__global__ __launch_bounds__(512, 1) void gate_main_kernel(
    const float* __restrict__ x, const short* __restrict__ wpk,
    float* __restrict__ out)
{
    // 8 waves x 3 bufs x 4KB = 96KB private staging; epilogue lg aliases it.
    __shared__ __align__(16) char smem[8 * 3 * 4096];

    const int tid = threadIdx.x;
    const int w   = tid >> 6;       // 8 waves
    const int l   = tid & 63;
    const int r31 = l & 31;
    const int l5  = l >> 5;
    const int tw  = w & 1;          // token half (32 tokens)
    const int kq  = w >> 1;         // K quarter 0..3
    const int bt0 = blockIdx.x * TT;

    char* wbase = smem + w * 12288;
    // read-side swizzle: SW(r) = (r&7) ^ (((r>>3)&3)<<1)
    const int swr = (r31 & 7) ^ (((r31 >> 3) & 3) << 1);

    const int srow = l >> 3;
    const int sg0  = (l & 7) ^ srow;   // ^ (2i) added per instr
    const float* xrow0 = x + (size_t)(bt0 + 32 * tw + srow) * DIMK + kq * 512;

#define STAGE_CHUNK(k) do {                                                   \
    _Pragma("unroll")                                                         \
    for (int i = 0; i < 4; ++i) {                                             \
        const float* gsrc = xrow0 + (size_t)(8 * i) * DIMK + (k) * 32         \
                          + ((sg0 ^ (2 * i)) << 2);                           \
        async16(wbase + ((k) % 3) * 4096 + i * 1024, gsrc);                   \
    }                                                                         \
} while (0)

    // W fragment pointers (packed, L2-hot): advance 3072 shorts per 16k slice
    const short* wq0 = wpk + (size_t)kq * 98304 + l * 8;   // n32=0 triple
    const short* wq1 = wq0 + 1536;                          // n32=1 triple

    f32x16 acc0, acc1;
#pragma unroll
    for (int i = 0; i < 16; ++i) { acc0[i] = 0.f; acc1[i] = 0.f; }

    u32x4 w0v[4][3], w1v[4][3];   // depth-3 slices, 4 banks (WAR-safe)

    // ---- prologue: st0, st1, st2, W0, W1, W2 ----
    STAGE_CHUNK(0);
    STAGE_CHUNK(1);
    STAGE_CHUNK(2);
    WLOAD3(w0v[0][0], w0v[0][1], w0v[0][2], wq0); wq0 += 3072;
    WLOAD3(w1v[0][0], w1v[0][1], w1v[0][2], wq1); wq1 += 3072;
    WLOAD3(w0v[1][0], w0v[1][1], w0v[1][2], wq0); wq0 += 3072;
    WLOAD3(w1v[1][0], w1v[1][1], w1v[1][2], wq1); wq1 += 3072;
    WLOAD3(w0v[2][0], w0v[2][1], w0v[2][2], wq0); wq0 += 3072;
    WLOAD3(w1v[2][0], w1v[2][1], w1v[2][2], wq1); wq1 += 3072;

    // ---- 32 slices, fully unrolled; FIFO-audited literal waits ----
#define SLICE(t) do {                                                         \
    if ((t) <= 28) {                                                          \
        WLOAD3(w0v[((t)+3)&3][0], w0v[((t)+3)&3][1], w0v[((t)+3)&3][2], wq0); \
        wq0 += 3072;                                                          \
        WLOAD3(w1v[((t)+3)&3][0], w1v[((t)+3)&3][1], w1v[((t)+3)&3][2], wq1); \
        wq1 += 3072;                                                          \
    }                                                                         \
    if ((t) <= 1)            WAITN(18);                                       \
    else if ((t) == 29)      WAITN(12);                                       \
    else if ((t) == 30)      WAITN(6);                                        \
    else if ((t) == 31)      WAITN(0);                                        \
    else if (((t) & 1) || (t) == 2 || (t) == 28) WAITN(22);                   \
    else                     WAITN(26);                                       \
    {                                                                         \
        const char* xb = wbase + (((t) >> 1) % 3) * 4096;                     \
        const float4 a0 = *(const float4*)(xb + r31 * 128 +                   \
            (((((t) & 1) * 4 + 2 * l5 + 0) ^ swr) << 4));                     \
        const float4 a1 = *(const float4*)(xb + r31 * 128 +                   \
            (((((t) & 1) * 4 + 2 * l5 + 1) ^ swr) << 4));                     \
        short8 H, M, L;                                                       \
        split3(a0, a1, H, M, L);                                              \
        acc0 = mfma6w(H, M, L, as_s8(w0v[(t)&3][0]), as_s8(w0v[(t)&3][1]),    \
                      as_s8(w0v[(t)&3][2]), acc0);                            \
        acc1 = mfma6w(H, M, L, as_s8(w1v[(t)&3][0]), as_s8(w1v[(t)&3][1]),    \
                      as_s8(w1v[(t)&3][2]), acc1);                            \
    }                                                                         \
    if (((t) & 1) && (t) <= 25) STAGE_CHUNK(((t) + 5) >> 1);                  \
} while (0)

    SLICE(0);  SLICE(1);  SLICE(2);  SLICE(3);
    SLICE(4);  SLICE(5);  SLICE(6);  SLICE(7);
    SLICE(8);  SLICE(9);  SLICE(10); SLICE(11);
    SLICE(12); SLICE(13); SLICE(14); SLICE(15);
    SLICE(16); SLICE(17); SLICE(18); SLICE(19);
    SLICE(20); SLICE(21); SLICE(22); SLICE(23);
    SLICE(24); SLICE(25); SLICE(26); SLICE(27);
    SLICE(28); SLICE(29); SLICE(30); SLICE(31);

    // ---- all waves done (lg aliases staging buffers) ----
    __syncthreads();

    // partials -> lg[kq][64][65]; C/D 32x32: col=l&31, row=(r&3)+8*(r>>2)+4*l5
    float* lg = (float*)smem;
#pragma unroll
    for (int r = 0; r < 16; ++r) {
        const int rowc = (r & 3) + 8 * (r >> 2) + 4 * l5;
        const int trow = 32 * tw + rowc;
        lg[(kq * TT + trow) * (NE + 1) + r31]      = acc0[r];
        lg[(kq * TT + trow) * (NE + 1) + 32 + r31] = acc1[r];
    }
    __syncthreads();

    // ---- deterministic 4-way K-split reduction: 4096 entries / 512 thr ----
#pragma unroll
    for (int rr = 0; rr < (TT * NE) / 512; ++rr) {
        const int idx = tid + rr * 512;
        const int t = idx >> 6, e = idx & 63;
        lg[t * (NE + 1) + e] =
            (lg[t * (NE + 1) + e] + lg[(TT + t) * (NE + 1) + e]) +
            (lg[(2 * TT + t) * (NE + 1) + e] + lg[(3 * TT + t) * (NE + 1) + e]);
    }
    __syncthreads();

    // ---- fused softmax + top-8: one lane per token ----
    if (tid < TT) {
        const float* rowp = lg + tid * (NE + 1);
        float mx = -3.402823466e38f;
        for (int e = 0; e < NE; ++e) mx = fmaxf(mx, rowp[e]);
        float sden = 0.f;
        for (int e = 0; e < NE; ++e) sden += expf(rowp[e] - mx);

        float tv[TOPKK];
        int   ti[TOPKK];
#pragma unroll
        for (int i = 0; i < TOPKK; ++i) { tv[i] = -3.402823466e38f; ti[i] = 0; }
        for (int e = 0; e < NE; ++e) {
            const float v = rowp[e];
            if (v > tv[TOPKK - 1]) {
                tv[TOPKK - 1] = v; ti[TOPKK - 1] = e;
#pragma unroll
                for (int q = TOPKK - 1; q > 0; --q) {
                    if (tv[q] > tv[q - 1]) {
                        const float fv = tv[q]; tv[q] = tv[q - 1]; tv[q - 1] = fv;
                        const int   iv = ti[q]; ti[q] = ti[q - 1]; ti[q - 1] = iv;
                    }
                }
            }
        }
        float* ow = out + (size_t)(bt0 + tid) * TOPKK;
        float* oi = out + (size_t)NT * TOPKK + (size_t)(bt0 + tid) * TOPKK;
#pragma unroll
        for (int i = 0; i < TOPKK; ++i) {
            ow[i] = expf(tv[i] - mx) / sden;   // ROUTE_SCALE == 1.0
            oi[i] = (float)ti[i];
        }
    }
#undef SLICE
#undef STAGE_CHUNK
}

// ================= fallback (R2 kernel) if ws too small =================
__device__ __forceinline__ f32x4 mfma6s(short8 ah, short8 am, short8 al,
                                        short8 bh, short8 bm, short8 bl, f32x4 c) {
    c = __builtin_amdgcn_mfma_f32_16x16x32_bf16(ah, bh, c, 0, 0, 0);
    c = __builtin_amdgcn_mfma_f32_16x16x32_bf16(ah, bm, c, 0, 0, 0);
    c = __builtin_amdgcn_mfma_f32_16x16x32_bf16(am, bh, c, 0, 0, 0);
    c = __builtin_amdgcn_mfma_f32_16x16x32_bf16(ah, bl, c, 0, 0, 0);
    c = __builtin_amdgcn_mfma_f32_16x16x32_bf16(am, bm, c, 0, 0, 0);
    c = __builtin_amdgcn_mfma_f32_16x16x32_bf16(al, bh, c, 0, 0, 0);
    return c;
}

__device__ __forceinline__ void load_step(const float* xp0, const float* xp1,
                                          const float* wp, int koff,
                                          float4 xb[2][2], float4 wb[4][2]) {
#pragma unroll
    for (int h = 0; h < 2; ++h) {
        xb[0][h] = *(const float4*)(xp0 + koff + 4 * h);
        xb[1][h] = *(const float4*)(xp1 + koff + 4 * h);
    }
#pragma unroll
    for (int n = 0; n < 4; ++n)
#pragma unroll
        for (int h = 0; h < 2; ++h)
            wb[n][h] = *(const float4*)(wp + (size_t)n * 16 * DIMK + koff + 4 * h);
}

__device__ __forceinline__ void do_step(const float4 xc[2][2], const float4 wc[4][2],
                                        f32x4 acc[2][4]) {
    short8 ah[2], am[2], al[2];
#pragma unroll
    for (int m = 0; m < 2; ++m) split3(xc[m][0], xc[m][1], ah[m], am[m], al[m]);
#pragma unroll
    for (int n = 0; n < 4; ++n) {
        short8 bh, bm, bl;
        split3(wc[n][0], wc[n][1], bh, bm, bl);
#pragma unroll
        for (int m = 0; m < 2; ++m)
            acc[m][n] = mfma6s(ah[m], am[m], al[m], bh, bm, bl, acc[m][n]);
    }
}

__global__ __launch_bounds__(256, 2) void gate_fallback_kernel(
    const float* __restrict__ x, const float* __restrict__ W,
    float* __restrict__ out)
{
    __shared__ float lg[4][32][NE + 1];
    const int tid = threadIdx.x;
    const int w = tid >> 6, l = tid & 63;
    const int j = l & 15, g = l >> 4;
    const int bt0 = blockIdx.x * 32;
    const int kb = w * 512;
    const float* xp0 = x + (size_t)(bt0 + j) * DIMK + kb + 8 * g;
    const float* xp1 = xp0 + (size_t)16 * DIMK;
    const float* wpp = W + (size_t)j * DIMK + kb + 8 * g;
    f32x4 acc[2][4];
#pragma unroll
    for (int m = 0; m < 2; ++m)
#pragma unroll
        for (int n = 0; n < 4; ++n) acc[m][n] = (f32x4){0.f, 0.f, 0.f, 0.f};
    float4 xA[2][2], wA[4][2], xB[2][2], wB[4][2];
    load_step(xp0, xp1, wpp, 0, xA, wA);
#pragma unroll 1
    for (int s = 0; s < 16; s += 2) {
        load_step(xp0, xp1, wpp, 32 * (s + 1), xB, wB);
        do_step(xA, wA, acc);
        if (s + 2 < 16) load_step(xp0, xp1, wpp, 32 * (s + 2), xA, wA);
        do_step(xB, wB, acc);
    }
#pragma unroll
    for (int m = 0; m < 2; ++m)
#pragma unroll
        for (int n = 0; n < 4; ++n)
#pragma unroll
            for (int q = 0; q < 4; ++q)
                lg[w][16 * m + 4 * g + q][16 * n + j] = acc[m][n][q];
    __syncthreads();
#pragma unroll
    for (int r = 0; r < 8; ++r) {
        const int idx = tid + r * 256;
        const int t = idx >> 6, e = idx & 63;
        lg[0][t][e] += lg[1][t][e] + lg[2][t][e] + lg[3][t][e];
    }
    __syncthreads();
    if (tid < 32) {
        const float* rowp = &lg[0][tid][0];
        float mx = -3.402823466e38f;
        for (int e = 0; e < NE; ++e) mx = fmaxf(mx, rowp[e]);
        float sden = 0.f;
        for (int e = 0; e < NE; ++e) sden += expf(rowp[e] - mx);
        float tv[TOPKK]; int ti[TOPKK];
#pragma unroll
        for (int i = 0; i < TOPKK; ++i) { tv[i] = -3.402823466e38f; ti[i] = 0; }
        for (int e = 0; e < NE; ++e) {
            const float v = rowp[e];
            if (v > tv[TOPKK - 1]) {
                tv[TOPKK - 1] = v; ti[TOPKK - 1] = e;
#pragma unroll
                for (int q = TOPKK - 1; q > 0; --q)
                    if (tv[q] > tv[q - 1]) {
                        const float fv = tv[q]; tv[q] = tv[q - 1]; tv[q - 1] = fv;
                        const int iv = ti[q]; ti[q] = ti[q - 1]; ti[q - 1] = iv;
                    }
            }
        }
        float* ow = out + (size_t)(bt0 + tid) * TOPKK;
        float* oi = out + (size_t)NT * TOPKK + (size_t)(bt0 + tid) * TOPKK;
#pragma unroll
        for (int i = 0; i < TOPKK; ++i) {
            ow[i] = expf(tv[i] - mx) / sden;
            oi[i] = (float)ti[i];
        }
    }
}

extern "C" void kernel_launch(void* const* d_in, const int* in_sizes, int n_in,
                              void* d_out, int out_size, void* d_ws, size_t ws_size,
                              hipStream_t stream) {
    const float* x = (const float*)d_in[0];
    const float* W = (const float*)d_in[1];
    float* out = (float*)d_out;
    if (ws_size >= (size_t)WS_BYTES) {
        short* wpk = (short*)d_ws;
        hipLaunchKernelGGL(pack_w_kernel, dim3(256), dim3(64), 0, stream, W, wpk);
        hipLaunchKernelGGL(gate_main_kernel, dim3(NT / TT), dim3(512), 0, stream,
                           x, wpk, out);
    } else {
        hipLaunchKernelGGL(gate_fallback_kernel, dim3(NT / 32), dim3(256), 0, stream,
                           x, W, out);
    }
}